// Round 1
// baseline (218.506 us; speedup 1.0000x reference)
//
#include <hip/hip_runtime.h>

// DecodeBox: B=16, A=3, ATTRS=6, D=H=W=48, stride=2 everywhere.
// in : [B, A*ATTRS, D, H, W] fp32   (channel stride = 110592 floats = 432 KB)
// out: [B, A*D*H*W, 6] fp32
//
// R3 structure (barrier-free wave-private streaming):
//  - The 1024-site tile transpose is WAVE-LOCAL: wave w's 64 lanes produce
//    exactly output float4s [384w, 384w+384) of the tile -- the same 6 KB
//    chunk that wave stores. So each wave gets a private 384-float4 LDS
//    region and the block barriers are replaced by a single
//    s_waitcnt lgkmcnt(0) (wave-scope, in-order, ~free). Zero s_barrier.
//  - Waves stream fully independently: load 6 -> compute -> 6 ds_write ->
//    lgkmcnt(0) -> 6 ds_read -> 6 NT stores, with next-tile loads
//    prefetched before the current tile's compute (cross-tile reg prefetch).
//  - TPB=4 (1296 blocks, ~5/CU fully co-resident at 24.6 KB LDS) amortizes
//    the un-overlapped prologue load.
//  - Nontemporal loads/stores: pure streaming, no reuse.
//  - Bank behavior identical to R2: conflicts are per-wave-instruction, the
//    per-wave index patterns are unchanged, and region bases 384*w are
//    8-aligned so the float4 XOR swizzle still applies within 8-blocks.

typedef float vf4 __attribute__((ext_vector_type(4)));

#define DHW    110592   // sites per (b,a) plane
#define HW48   2304
#define SPB    1024     // sites per tile (256 threads x 4 sites)
#define BPP    108      // tiles per plane
#define F4B    1536     // float4s per tile (1024*6/4)
#define F4P    165888   // float4s per plane
#define CH4    27648    // channel stride in float4 units (DHW/4)
#define TPB    4        // tiles per block
#define NBLK   1296     // 5184 tiles / 4
#define WREG   384      // float4s per wave-private LDS region (6 KB)

struct Frag { vf4 x, y, z, l, c, k; };

__device__ __forceinline__ float sigm(float v) {
    return 1.0f / (1.0f + __expf(-v));
}

// float4-granular XOR swizzle: lane-linear reads conflict-free, stride-6
// writes spread over all 8 4-bank groups. Pure permutation within each
// 8-float4 block, so it composes with any 8-aligned region base.
__device__ __forceinline__ int swz(int i) {
    return (i & ~7) | ((i ^ (i >> 3)) & 7);
}

__device__ __forceinline__ void load_frag(const float* __restrict__ in, int T,
                                          int tid, Frag& f) {
    const int p = T / BPP;          // (b,a) plane, 0..47
    const int chunk = T - p * BPP;  // 0..107
    const vf4* ip = (const vf4*)(in + (size_t)p * (6 * DHW) + chunk * SPB) + tid;
    f.x = __builtin_nontemporal_load(ip + 0 * CH4);
    f.y = __builtin_nontemporal_load(ip + 1 * CH4);
    f.z = __builtin_nontemporal_load(ip + 2 * CH4);
    f.l = __builtin_nontemporal_load(ip + 3 * CH4);
    f.c = __builtin_nontemporal_load(ip + 4 * CH4);
    f.k = __builtin_nontemporal_load(ip + 5 * CH4);
}

__device__ __forceinline__ void process(float* __restrict__ out, int T, int tid,
                                        const Frag& f, vf4* __restrict__ wlds) {
    const int p = T / BPP;
    const int chunk = T - p * BPP;
    const int a = p % 3;
    const float anchw = (a == 0) ? 4.0f : (a == 1) ? 8.0f : 16.0f;
    const int S = chunk * SPB + tid * 4;      // first of 4 consecutive sites
    const float xf = (float)(S % 48);         // S multiple of 4: no row wrap
    const float yf = (float)((S / 48) % 48);
    const float zf = (float)(S / HW48);

    float bx[4], by[4], bz[4], bl[4], cf[4], cl[4];
#pragma unroll
    for (int q = 0; q < 4; ++q) {
        bx[q] = (sigm(f.x[q]) + xf + (float)q) * 2.0f;
        by[q] = (sigm(f.y[q]) + yf) * 2.0f;
        bz[q] = (sigm(f.z[q]) + zf) * 2.0f;
        bl[q] = __expf(f.l[q]) * anchw;  // exp(l) * (anchor_w/stride) * stride
        cf[q] = sigm(f.c[q]);
        cl[q] = sigm(f.k[q]);
    }

    const int lane = tid & 63;
    const int wb = 6 * lane;
    wlds[swz(wb + 0)] = (vf4){bx[0], by[0], bz[0], bl[0]};
    wlds[swz(wb + 1)] = (vf4){cf[0], cl[0], bx[1], by[1]};
    wlds[swz(wb + 2)] = (vf4){bz[1], bl[1], cf[1], cl[1]};
    wlds[swz(wb + 3)] = (vf4){bx[2], by[2], bz[2], bl[2]};
    wlds[swz(wb + 4)] = (vf4){cf[2], cl[2], bx[3], by[3]};
    wlds[swz(wb + 5)] = (vf4){bz[3], bl[3], cf[3], cl[3]};

    // Wave-private region: producer lanes == consumer lanes (same wave, one
    // exec mask, lockstep issue). Draining THIS wave's DS ops is the entire
    // synchronization requirement -- no s_barrier anywhere in the kernel.
    asm volatile("s_waitcnt lgkmcnt(0)" ::: "memory");

    vf4* op = (vf4*)out + (size_t)p * F4P + (size_t)chunk * F4B + (tid >> 6) * WREG;
#pragma unroll
    for (int kk = 0; kk < 6; ++kk) {
        const int i = lane + 64 * kk;
        __builtin_nontemporal_store(wlds[swz(i)], op + i);
    }
    // No trailing sync needed: the NT stores consumed the ds_read results,
    // so all 6 reads have retired before the next tile's ds_writes issue
    // (WAR on the wave-private region is ordered through the registers).
}

__global__ __launch_bounds__(256) void DecodeBox_kernel(
    const float* __restrict__ in, float* __restrict__ out) {
    __shared__ vf4 lds[F4B];
    const int tid = threadIdx.x;
    vf4* wlds = lds + (tid >> 6) * WREG;   // 6 KB wave-private region
    const int T0 = blockIdx.x * TPB;

    Frag A, B;
    load_frag(in, T0, tid, A);
#pragma unroll
    for (int t = 0; t < TPB; ++t) {
        if (t + 1 < TPB) load_frag(in, T0 + t + 1, tid, B);  // prefetch
        process(out, T0 + t, tid, A, wlds);
        A = B;  // renamed away by full unroll
    }
}

extern "C" void kernel_launch(void* const* d_in, const int* in_sizes, int n_in,
                              void* d_out, int out_size, void* d_ws, size_t ws_size,
                              hipStream_t stream) {
    const float* in = (const float*)d_in[0];
    float* out = (float*)d_out;
    DecodeBox_kernel<<<NBLK, 256, 0, stream>>>(in, out);
}

// Round 2
// 208.153 us; speedup vs baseline: 1.0497x; 1.0497x over previous
//
#include <hip/hip_runtime.h>

// DecodeBox: B=16, A=3, ATTRS=6, D=H=W=48, stride=2 everywhere.
// in : [B, A*ATTRS, D, H, W] fp32   (channel stride = 110592 floats = 432 KB)
// out: [B, A*D*H*W, 6] fp32
//
// R4 structure (finest-grain barrier-free streaming):
//  - TPB=1: 5184 blocks of one 1024-site tile each (~20 blocks/CU queued,
//    6 co-resident by LDS). R3's TPB=4 (1296 blocks = 5.06/CU) put the whole
//    grid resident in one dispatch wave -> no rebalancing; 16 CUs got 6
//    blocks vs 5 elsewhere -> +18% tail (matched the observed +8 us).
//    1-tile granularity lets the dispatcher self-balance to ~1%.
//  - Wave-local transpose (from R3): wave w's 64 lanes produce exactly
//    output float4s [384w, 384w+384) of the tile, so each wave uses a
//    private 384-float4 LDS region and the only sync is a wave-scope
//    s_waitcnt lgkmcnt(0). Zero s_barrier -> waves retire independently,
//    shrinking the tail further (scheduling quantum = wave, not block).
//  - Nontemporal loads/stores: pure streaming, no reuse.
//  - float4 XOR swizzle keeps both the stride-6 LDS writes and the
//    lane-linear LDS reads conflict-free (pure permutation within each
//    8-float4 block; region bases 384w are 8-aligned).

typedef float vf4 __attribute__((ext_vector_type(4)));

#define DHW    110592   // sites per (b,a) plane
#define HW48   2304
#define SPB    1024     // sites per tile (256 threads x 4 sites)
#define BPP    108      // tiles per plane
#define F4B    1536     // float4s per tile (1024*6/4)
#define F4P    165888   // float4s per plane
#define CH4    27648    // channel stride in float4 units (DHW/4)
#define NBLK   5184     // one tile per block
#define WREG   384      // float4s per wave-private LDS region (6 KB)

struct Frag { vf4 x, y, z, l, c, k; };

__device__ __forceinline__ float sigm(float v) {
    return 1.0f / (1.0f + __expf(-v));
}

// float4-granular XOR swizzle: lane-linear reads conflict-free, stride-6
// writes spread over all 8 4-bank groups. Pure permutation within each
// 8-float4 block, so it composes with any 8-aligned region base.
__device__ __forceinline__ int swz(int i) {
    return (i & ~7) | ((i ^ (i >> 3)) & 7);
}

__device__ __forceinline__ void load_frag(const float* __restrict__ in, int T,
                                          int tid, Frag& f) {
    const int p = T / BPP;          // (b,a) plane, 0..47
    const int chunk = T - p * BPP;  // 0..107
    const vf4* ip = (const vf4*)(in + (size_t)p * (6 * DHW) + chunk * SPB) + tid;
    f.x = __builtin_nontemporal_load(ip + 0 * CH4);
    f.y = __builtin_nontemporal_load(ip + 1 * CH4);
    f.z = __builtin_nontemporal_load(ip + 2 * CH4);
    f.l = __builtin_nontemporal_load(ip + 3 * CH4);
    f.c = __builtin_nontemporal_load(ip + 4 * CH4);
    f.k = __builtin_nontemporal_load(ip + 5 * CH4);
}

__device__ __forceinline__ void process(float* __restrict__ out, int T, int tid,
                                        const Frag& f, vf4* __restrict__ wlds) {
    const int p = T / BPP;
    const int chunk = T - p * BPP;
    const int a = p % 3;
    const float anchw = (a == 0) ? 4.0f : (a == 1) ? 8.0f : 16.0f;
    const int S = chunk * SPB + tid * 4;      // first of 4 consecutive sites
    const float xf = (float)(S % 48);         // S multiple of 4: no row wrap
    const float yf = (float)((S / 48) % 48);
    const float zf = (float)(S / HW48);

    float bx[4], by[4], bz[4], bl[4], cf[4], cl[4];
#pragma unroll
    for (int q = 0; q < 4; ++q) {
        bx[q] = (sigm(f.x[q]) + xf + (float)q) * 2.0f;
        by[q] = (sigm(f.y[q]) + yf) * 2.0f;
        bz[q] = (sigm(f.z[q]) + zf) * 2.0f;
        bl[q] = __expf(f.l[q]) * anchw;  // exp(l) * (anchor_w/stride) * stride
        cf[q] = sigm(f.c[q]);
        cl[q] = sigm(f.k[q]);
    }

    const int lane = tid & 63;
    const int wb = 6 * lane;
    wlds[swz(wb + 0)] = (vf4){bx[0], by[0], bz[0], bl[0]};
    wlds[swz(wb + 1)] = (vf4){cf[0], cl[0], bx[1], by[1]};
    wlds[swz(wb + 2)] = (vf4){bz[1], bl[1], cf[1], cl[1]};
    wlds[swz(wb + 3)] = (vf4){bx[2], by[2], bz[2], bl[2]};
    wlds[swz(wb + 4)] = (vf4){cf[2], cl[2], bx[3], by[3]};
    wlds[swz(wb + 5)] = (vf4){bz[3], bl[3], cf[3], cl[3]};

    // Wave-private region: producer lanes == consumer lanes (same wave, one
    // exec mask, lockstep issue). Draining THIS wave's DS ops is the entire
    // synchronization requirement -- no s_barrier anywhere in the kernel.
    asm volatile("s_waitcnt lgkmcnt(0)" ::: "memory");

    vf4* op = (vf4*)out + (size_t)p * F4P + (size_t)chunk * F4B + (tid >> 6) * WREG;
#pragma unroll
    for (int kk = 0; kk < 6; ++kk) {
        const int i = lane + 64 * kk;
        __builtin_nontemporal_store(wlds[swz(i)], op + i);
    }
}

__global__ __launch_bounds__(256) void DecodeBox_kernel(
    const float* __restrict__ in, float* __restrict__ out) {
    __shared__ vf4 lds[F4B];
    const int tid = threadIdx.x;
    vf4* wlds = lds + (tid >> 6) * WREG;   // 6 KB wave-private region
    const int T = blockIdx.x;              // one tile per block

    Frag f;
    load_frag(in, T, tid, f);
    process(out, T, tid, f, wlds);
}

extern "C" void kernel_launch(void* const* d_in, const int* in_sizes, int n_in,
                              void* d_out, int out_size, void* d_ws, size_t ws_size,
                              hipStream_t stream) {
    const float* in = (const float*)d_in[0];
    float* out = (float*)d_out;
    DecodeBox_kernel<<<NBLK, 256, 0, stream>>>(in, out);
}